// Round 1
// 165.716 us; speedup vs baseline: 1.0013x; 1.0013x over previous
//
#include <hip/hip_runtime.h>

// DynamicDilationUnfold: B=4, C=64, H=W=128, G=4, Cg=16, K=3, stride=1, pad=1.
// out[b][((g*Cg+cg)*K+kh)*K+kw][ho*Wo+wo], fp32.
//
// R5: issue/latency overhaul. rocprof shows poison fills at 6.76 TB/s (89 us);
// kernel is <89 us vs a 26 us write floor -> not BW-bound, gather-loop bound.
//   - channel-interleaved float4 LDS: 1x ds_read_b128 per bilinear corner
//     serves all 4 channels (DS insts halved), staging writes become linear
//   - XOR quad swizzle (q ^= (q>>2)&7) on BOTH write and read sides: breaks
//     the stride-8-dword bank clustering of the b128 gather
//   - 256-thr blocks, 8x64 tile, 15.7 KB LDS, grid=2048 -> ~6 blocks/CU
//     resident, 8 assigned -> inter-block stage/compute/store overlap
//   - __launch_bounds__(256,6): VGPR cap 84 (was 64) so the scheduler can
//     hoist reads across (kh,kw) iterations without spilling

constexpr int B  = 4;
constexpr int C  = 64;
constexpr int H  = 128;
constexpr int W  = 128;
constexpr int G  = 4;
constexpr int Cg = C / G;            // 16
constexpr int K  = 3;
constexpr int KK = K * K;
constexpr int Ho = 128;
constexpr int Wo = 128;
constexpr int HW = H * W;            // 16384
constexpr int HoWo = Ho * Wo;        // 16384

constexpr int TILE_H = 8;
constexpr int TILE_W = 64;
constexpr int CPB    = 4;            // channels per block (interleaved in LDS)
constexpr int REG_H  = TILE_H + 6;   // 14 rows (halo -1 .. +5; max r = 13)
constexpr int REG_W  = TILE_W + 6;   // 70 cols (max c = 69)
constexpr int NQUAD  = REG_H * REG_W;          // 980 float4 quads
constexpr int NQUAD_PAD = (NQUAD + 7) & ~7;    // 984: XOR swizzle 8-quad window
constexpr int NTHREADS  = 256;

// bijective quad swizzle: flips quad bits[2:0] with bits[4:2] -> spreads the
// stride-8-dword gather pattern across all bank groups; involution-consistent
// because both write and read compute it from the same linear quad index.
__device__ __forceinline__ int swz(int q) { return q ^ ((q >> 2) & 7); }

__global__ __launch_bounds__(NTHREADS, 6) void ddu_kernel(
    const float* __restrict__ x,      // (B, C, H, W)
    const float* __restrict__ dmap,   // (B, G, H, W)
    float* __restrict__ out)          // (B, C*K*K, Ho*Wo)
{
    __shared__ float4 lds4[NQUAD_PAD];           // 15,744 B

    const int tid   = threadIdx.x;
    const int bid   = blockIdx.x;                // 2048 = b(4) g(4) chunk(4) th(16) tw(2)
    const int tw    = bid & 1;
    const int th    = (bid >> 1) & 15;
    const int chunk = (bid >> 5) & 3;
    const int g     = (bid >> 7) & 3;
    const int b     = bid >> 9;

    const int ho0 = th * TILE_H;
    const int wo0 = tw * TILE_W;

    const float* __restrict__ xg = x + (size_t)(b * C + g * Cg + chunk * CPB) * HW;

    // ---- stage: 4 coalesced per-channel loads -> one linear ds_write_b128 ----
    const int r_img0 = ho0 - 1;
    const int c_img0 = wo0 - 1;
#pragma unroll
    for (int it = 0; it < (NQUAD + NTHREADS - 1) / NTHREADS; ++it) {
        const int p = it * NTHREADS + tid;
        if (p < NQUAD) {
            const int r  = p / REG_W;
            const int c  = p - r * REG_W;
            const int ir = r_img0 + r;
            const int ic = c_img0 + c;
            float4 v = make_float4(0.f, 0.f, 0.f, 0.f);
            if ((unsigned)ir < (unsigned)H && (unsigned)ic < (unsigned)W) {
                const float* __restrict__ s = xg + ir * W + ic;
                v.x = s[0];
                v.y = s[HW];
                v.z = s[2 * HW];
                v.w = s[3 * HW];
            }
            lds4[swz(p)] = v;                    // zero-filled halo == validity mask
        }
    }
    __syncthreads();

    // ---- compute: each thread owns 2 adjacent wo (own d each) ----
    const int wi2 = tid & 31;                    // wo-pair 0..31
    const int hi  = tid >> 5;                    // 0..7
    const int ho  = ho0 + hi;
    const int wo  = wo0 + wi2 * 2;

    const float2 dv = *(const float2*)&dmap[(size_t)(b * G + g) * HoWo + ho * Wo + wo];
    const float d0 = dv.x;
    const float d1 = dv.y;

    float* __restrict__ outb = out
        + (size_t)((b * C + g * Cg + chunk * CPB) * KK) * HoWo
        + (size_t)(ho * Wo + wo);

    const float col0 = (float)(wi2 * 2);         // local col of subpixel 0
    const float col1 = (float)(wi2 * 2 + 1);
    const float rowf = (float)hi;

#pragma unroll
    for (int kh = 0; kh < K; ++kh) {
        const float ph0 = rowf + (float)kh * d0;
        const float ph1 = rowf + (float)kh * d1;
        const int   r0  = (int)ph0;              // >= 0 always (d > 0)
        const int   r1  = (int)ph1;
        const float lh0 = ph0 - (float)r0;
        const float lh1 = ph1 - (float)r1;
        const float mh0 = 1.f - lh0;
        const float mh1 = 1.f - lh1;

#pragma unroll
        for (int kw = 0; kw < K; ++kw) {
            const float pw0 = col0 + (float)kw * d0;
            const float pw1 = col1 + (float)kw * d1;
            const int   c0  = (int)pw0;
            const int   c1  = (int)pw1;
            const float lw0 = pw0 - (float)c0;
            const float lw1 = pw1 - (float)c1;

            const int qa = r0 * REG_W + c0;      // <= 13*70+68, +REG_W+1 <= 979
            const int qb = r1 * REG_W + c1;

            // subpixel 0: 4 corners x 4 channels via 4x ds_read_b128
            const float4 va00 = lds4[swz(qa)];
            const float4 va01 = lds4[swz(qa + 1)];
            const float4 va10 = lds4[swz(qa + REG_W)];
            const float4 va11 = lds4[swz(qa + REG_W + 1)];

            const float a00 = mh0 * (1.f - lw0);
            const float a01 = mh0 * lw0;
            const float a10 = lh0 * (1.f - lw0);
            const float a11 = lh0 * lw0;

            const float s0x = a00 * va00.x + a01 * va01.x + a10 * va10.x + a11 * va11.x;
            const float s0y = a00 * va00.y + a01 * va01.y + a10 * va10.y + a11 * va11.y;
            const float s0z = a00 * va00.z + a01 * va01.z + a10 * va10.z + a11 * va11.z;
            const float s0w = a00 * va00.w + a01 * va01.w + a10 * va10.w + a11 * va11.w;

            // subpixel 1
            const float4 vb00 = lds4[swz(qb)];
            const float4 vb01 = lds4[swz(qb + 1)];
            const float4 vb10 = lds4[swz(qb + REG_W)];
            const float4 vb11 = lds4[swz(qb + REG_W + 1)];

            const float b00 = mh1 * (1.f - lw1);
            const float b01 = mh1 * lw1;
            const float b10 = lh1 * (1.f - lw1);
            const float b11 = lh1 * lw1;

            const float s1x = b00 * vb00.x + b01 * vb01.x + b10 * vb10.x + b11 * vb11.x;
            const float s1y = b00 * vb00.y + b01 * vb01.y + b10 * vb10.y + b11 * vb11.y;
            const float s1z = b00 * vb00.z + b01 * vb01.z + b10 * vb10.z + b11 * vb11.z;
            const float s1w = b00 * vb00.w + b01 * vb01.w + b10 * vb10.w + b11 * vb11.w;

            float* __restrict__ o = outb + (size_t)(kh * K + kw) * HoWo;
            *(float2*)(o)                         = make_float2(s0x, s1x);
            *(float2*)(o + (size_t)1 * KK * HoWo) = make_float2(s0y, s1y);
            *(float2*)(o + (size_t)2 * KK * HoWo) = make_float2(s0z, s1z);
            *(float2*)(o + (size_t)3 * KK * HoWo) = make_float2(s0w, s1w);
        }
    }
}

extern "C" void kernel_launch(void* const* d_in, const int* in_sizes, int n_in,
                              void* d_out, int out_size, void* d_ws, size_t ws_size,
                              hipStream_t stream) {
    const float* x    = (const float*)d_in[0];
    const float* dmap = (const float*)d_in[1];
    float* out = (float*)d_out;

    const int grid = B * G * (Cg / CPB) * (Ho / TILE_H) * (Wo / TILE_W);   // 2048
    ddu_kernel<<<grid, NTHREADS, 0, stream>>>(x, dmap, out);
}